// Round 10
// baseline (298.306 us; speedup 1.0000x reference)
//
#include <hip/hip_runtime.h>
#include <math.h>

#define NT 32
#define NQ 256
#define NN 8192
#define DD 128
#define CHN 32
#define KK 16
#define NBB 8
#define NBATCH 4
#define CAP 128   // candidate cap per (wave,t); observed ncand ~30-60
#define TFUSE 4   // t's fused per selection wave

// Persistent device scratch (fully rewritten every launch)
__device__ float g_NF2[NN * DD];     // node_feature @ W_ext (gate applied in epi)
__device__ float g_gate[DD];
__device__ float g_coef[192];        // Al,Bl,Cl,Aa,Ba,Ca  (6 x 32)
__device__ int   g_bstart[NBATCH];
__device__ int   g_bend[NBATCH];
__device__ int   g_kidx[NT * NQ * KK];  // top-16 node idx per (t,q)  [select->epi]
__device__ float g_kd[NT * NQ * KK];    // top-16 distance per (t,q)  [select->epi]
__device__ float g_accA[NT * 3];
__device__ float g_accL[NT * 3];

__device__ __forceinline__ void quat_rot(float w, float x, float y, float z,
                                         float v0, float v1, float v2,
                                         float& r0, float& r1, float& r2) {
  float uv0 = y * v2 - z * v1;
  float uv1 = z * v0 - x * v2;
  float uv2 = x * v1 - y * v0;
  float uuv0 = y * uv2 - z * uv1;
  float uuv1 = z * uv0 - x * uv2;
  float uuv2 = x * uv1 - y * uv0;
  r0 = v0 + 2.0f * (w * uv0 + uuv0);
  r1 = v1 + 2.0f * (w * uv1 + uuv1);
  r2 = v2 + 2.0f * (w * uv2 + uuv2);
}

__device__ __forceinline__ void quat_rot_d(double w, double x, double y, double z,
                                           double v0, double v1, double v2,
                                           double& r0, double& r1, double& r2) {
  double uv0 = y * v2 - z * v1;
  double uv1 = z * v0 - x * v2;
  double uv2 = x * v1 - y * v0;
  double uuv0 = y * uv2 - z * uv1;
  double uuv1 = z * uv0 - x * uv2;
  double uuv2 = x * uv1 - y * uv0;
  r0 = v0 + 2.0 * (w * uv0 + uuv0);
  r1 = v1 + 2.0 * (w * uv1 + uuv1);
  r2 = v2 + 2.0 * (w * uv2 + uuv2);
}

// Blocks 0..511: NF2[n,j] = sum_d nf[n,d]*W_ext[d,j]  (gate applied in epi)
// Block 512: setup — r3-proven write-only globals.
__global__ __launch_bounds__(256) void prep_kernel(
    const float* __restrict__ nf, const float* __restrict__ W_ext,
    const int* __restrict__ node_batch, const float* __restrict__ time_emb,
    const float* __restrict__ W_time,
    const float* __restrict__ w_path_lin, const float* __restrict__ W_vec_lin,
    const float* __restrict__ w_path_ang, const float* __restrict__ W_vec_ang) {
  int tid = threadIdx.x;
  if (blockIdx.x == 512) {
    if (tid < 96) g_accA[tid] = 0.0f;
    else if (tid < 192) g_accL[tid - 96] = 0.0f;
    if (tid < NBATCH) { g_bstart[tid] = 0; g_bend[tid] = 0; }
    __syncthreads();
    // node_batch sorted: contiguous segment boundaries, unique writer per batch
    for (int i = tid; i < NN; i += 256) {
      int v = node_batch[i];
      if (i == 0 || node_batch[i - 1] != v) g_bstart[v] = i;
      if (i == NN - 1 || node_batch[i + 1] != v) g_bend[v] = i + 1;
    }
    // gate[j] = 1 + (time_emb @ W_time)[j]
    if (tid < DD) {
      float g = 0.0f;
      for (int d = 0; d < DD; d++) g += time_emb[d] * W_time[d * DD + tid];
      g_gate[tid] = 1.0f + g;
    }
    // DTP collapse: [:,1:] kills scal path; mean over out-channels collapses W_vec.
    if (tid < 192) {
      int arr = tid >> 5, c = tid & 31;
      int path = (arr >= 3) ? (arr - 3) : arr;
      const float* Wv = (arr < 3) ? W_vec_lin : W_vec_ang;
      const float* wp = (arr < 3) ? w_path_lin : w_path_ang;
      float s = 0.0f;
      for (int o = 0; o < CHN; o++) s += Wv[(path * CHN + c) * CHN + o];
      g_coef[tid] = wp[(2 + path) * CHN + c] * (s * (1.0f / 32.0f));
    }
    return;
  }
  int gid = blockIdx.x * 256 + tid;
  int j = gid & (DD - 1);
  int n0 = (gid >> 7) * 8;
  n0 = __builtin_amdgcn_readfirstlane(n0);
  float acc[8] = {0, 0, 0, 0, 0, 0, 0, 0};
  const float* nfr = nf + (long)n0 * DD;
#pragma unroll 4
  for (int d = 0; d < DD; d++) {
    float w = W_ext[d * DD + j];
#pragma unroll
    for (int rr = 0; rr < 8; rr++) acc[rr] += nfr[rr * DD + d] * w;
  }
#pragma unroll
  for (int rr = 0; rr < 8; rr++) g_NF2[(n0 + rr) * DD + j] = acc[rr];
}

// Selection only (r9-verbatim passes A/B/C): one wave per (q, tg), TFUSE=4 t's
// fused so nodes are loaded once per pass for 4 t's. Writes the exact top-16
// (node idx, fp64-ordered distance) per (t,q) to global scratch. Wave-private
// LDS, no barriers.
__global__ __launch_bounds__(256) void select_kernel(
    const float* __restrict__ Tm,
    const float* __restrict__ qcoord,
    const float* __restrict__ ncoord,
    const int* __restrict__ qbatch) {
  __shared__ int s_cidx[4][TFUSE][CAP];

  int lane = threadIdx.x & 63;
  int wid = threadIdx.x >> 6;
  int w = blockIdx.x * 4 + wid;      // wave id in [0, 2048)
  int q = w >> 3;                     // [0, 256)
  int tg = w & 7;                     // [0, 8); t = tg*4 + tt

  float c0 = qcoord[q * 3 + 0], c1 = qcoord[q * 3 + 1], c2 = qcoord[q * 3 + 2];
  int b = qbatch[q];
  int sBeg = g_bstart[b], sEnd = g_bend[b];

  // fp32 transformed query points for the 4 fused t's (cast from fp64)
  float pf0[TFUSE], pf1[TFUSE], pf2[TFUSE];
#pragma unroll
  for (int tt = 0; tt < TFUSE; tt++) {
    int t = tg * TFUSE + tt;
    double dr0, dr1, dr2;
    quat_rot_d((double)Tm[t * 7 + 0], (double)Tm[t * 7 + 1],
               (double)Tm[t * 7 + 2], (double)Tm[t * 7 + 3],
               (double)c0, (double)c1, (double)c2, dr0, dr1, dr2);
    pf0[tt] = (float)(dr0 + (double)Tm[t * 7 + 4]);
    pf1[tt] = (float)(dr1 + (double)Tm[t * 7 + 5]);
    pf2[tt] = (float)(dr2 + (double)Tm[t * 7 + 6]);
  }

  // Pass A: per-lane min d2 for 4 t's, nodes loaded once, 4-way node interleave
  float lm[TFUSE];
#pragma unroll
  for (int tt = 0; tt < TFUSE; tt++) lm[tt] = 3.0e38f;
  for (int i = sBeg + lane; i < sEnd; i += 256) {
#pragma unroll
    for (int sub = 0; sub < 4; sub++) {
      int ii = i + (sub << 6);
      if (ii < sEnd) {
        float x = ncoord[3 * ii + 0];
        float y = ncoord[3 * ii + 1];
        float z = ncoord[3 * ii + 2];
#pragma unroll
        for (int tt = 0; tt < TFUSE; tt++) {
          float dx = pf0[tt] - x, dy = pf1[tt] - y, dz = pf2[tt] - z;
          lm[tt] = fminf(lm[tt], dx * dx + dy * dy + dz * dz);
        }
      }
    }
  }

  // per-t bitonic over 64 lane minima; thr = 16th smallest + slack
  float thrv[TFUSE];
#pragma unroll
  for (int tt = 0; tt < TFUSE; tt++) {
    float v = lm[tt];
#pragma unroll
    for (int k = 2; k <= 64; k <<= 1) {
#pragma unroll
      for (int j = k >> 1; j > 0; j >>= 1) {
        float o = __shfl_xor(v, j, 64);
        bool keep_min = (((lane & j) == 0) == ((lane & k) == 0));
        v = keep_min ? fminf(v, o) : fmaxf(v, o);
      }
    }
    thrv[tt] = __shfl(v, 15, 64) + 1.0e-3f;
  }

  // Pass B: fused compaction — nodes loaded once, 4 ballots per chunk
  int base[TFUSE];
#pragma unroll
  for (int tt = 0; tt < TFUSE; tt++) base[tt] = 0;
  for (int i0 = sBeg; i0 < sEnd; i0 += 64) {
    int i = i0 + lane;
    bool inb = (i < sEnd);
    float x = 0.0f, y = 0.0f, z = 0.0f;
    if (inb) {
      x = ncoord[3 * i + 0];
      y = ncoord[3 * i + 1];
      z = ncoord[3 * i + 2];
    }
#pragma unroll
    for (int tt = 0; tt < TFUSE; tt++) {
      bool pred = false;
      if (inb) {
        float dx = pf0[tt] - x, dy = pf1[tt] - y, dz = pf2[tt] - z;
        pred = (dx * dx + dy * dy + dz * dz) <= thrv[tt];
      }
      unsigned long long bal = __ballot(pred);
      int pre = __popcll(bal & ((1ull << lane) - 1ull));
      if (pred) {
        int pos = base[tt] + pre;
        if (pos < CAP) s_cidx[wid][tt][pos] = i;
      }
      base[tt] += __popcll(bal);
    }
  }

  // Pass C per t: exact fp64 ordering; write top-16 (idx, d) to global.
  for (int tt = 0; tt < TFUSE; tt++) {
    int t = tg * TFUSE + tt;
    double dr0, dr1, dr2;
    quat_rot_d((double)Tm[t * 7 + 0], (double)Tm[t * 7 + 1],
               (double)Tm[t * 7 + 2], (double)Tm[t * 7 + 3],
               (double)c0, (double)c1, (double)c2, dr0, dr1, dr2);
    double p0 = dr0 + (double)Tm[t * 7 + 4];
    double p1 = dr1 + (double)Tm[t * 7 + 5];
    double p2 = dr2 + (double)Tm[t * 7 + 6];
    int ncand = base[tt] < CAP ? base[tt] : CAP;
    int obase = (t * NQ + q) * KK;

    if (ncand <= 64) {
      unsigned long long key = ~0ull;
      if (lane < ncand) {
        int idx = s_cidx[wid][tt][lane];
        double dx = p0 - (double)ncoord[3 * idx + 0];
        double dy = p1 - (double)ncoord[3 * idx + 1];
        double dz = p2 - (double)ncoord[3 * idx + 2];
        double d2 = dx * dx + dy * dy + dz * dz;
        key = (((unsigned long long)__double_as_longlong(d2)) & ~0x1FFFull) |
              (unsigned long long)idx;
      }
#pragma unroll
      for (int k = 2; k <= 64; k <<= 1) {
#pragma unroll
        for (int j = k >> 1; j > 0; j >>= 1) {
          unsigned long long o = __shfl_xor(key, j, 64);
          bool keep_min = (((lane & j) == 0) == ((lane & k) == 0));
          unsigned long long mn = o < key ? o : key;
          unsigned long long mx = o < key ? key : o;
          key = keep_min ? mn : mx;
        }
      }
      if (lane < KK) {
        double d2m = __longlong_as_double((long long)(key & ~0x1FFFull));
        g_kidx[obase + lane] = (int)(key & 0x1FFFull);
        g_kd[obase + lane] = (float)sqrt(fmax(d2m, 1.0e-12));
      }
    } else {  // rare: 64 < ncand <= 128 — serial 16-extraction over 2 key slots
      unsigned long long key[2];
#pragma unroll
      for (int s = 0; s < 2; s++) {
        int pos = lane + 64 * s;
        if (pos < ncand) {
          int idx = s_cidx[wid][tt][pos];
          double dx = p0 - (double)ncoord[3 * idx + 0];
          double dy = p1 - (double)ncoord[3 * idx + 1];
          double dz = p2 - (double)ncoord[3 * idx + 2];
          double d2 = dx * dx + dy * dy + dz * dz;
          key[s] = (((unsigned long long)__double_as_longlong(d2)) & ~0x1FFFull) |
                   (unsigned long long)idx;
        } else {
          key[s] = ~0ull;
        }
      }
      for (int r = 0; r < KK; r++) {
        unsigned long long kmin = key[0] < key[1] ? key[0] : key[1];
#pragma unroll
        for (int off = 32; off > 0; off >>= 1) {
          unsigned long long o = __shfl_xor(kmin, off, 64);
          kmin = (o < kmin) ? o : kmin;
        }
        if (lane == 0) {
          double d2m = __longlong_as_double((long long)(kmin & ~0x1FFFull));
          g_kidx[obase + r] = (int)(kmin & 0x1FFFull);
          g_kd[obase + r] = (float)sqrt(fmax(d2m, 1.0e-12));
        }
#pragma unroll
        for (int s = 0; s < 2; s++)
          if (key[s] == kmin) key[s] = ~0ull;
      }
    }
  }
}

// Epilogue: one wave per (t,q) — 8192 waves (32/CU) so the scattered NF2 row
// loads and LDS chains are latency-hidden. rbf/field/DTP/accumulate verbatim
// from the r9-passed kernel; input moves from LDS to g_kidx/g_kd.
__global__ __launch_bounds__(256) void epi_kernel(
    const float* __restrict__ Tm,
    const float* __restrict__ qwgt,
    const float* __restrict__ qfeat,
    const float* __restrict__ qcoord,
    const float* __restrict__ W_rbf) {
  __shared__ float s_kd[4][KK];
  __shared__ int s_kidx[4][KK];
  __shared__ float s_rbf[4][KK * NBB];
  __shared__ float s_field[4][DD];

  int lane = threadIdx.x & 63;
  int wid = threadIdx.x >> 6;
  int m = blockIdx.x * 4 + wid;
  int t = m >> 8, q = m & (NQ - 1);
  int obase = m * KK;  // m == t*NQ + q

  float Qw = Tm[t * 7 + 0], Qx = Tm[t * 7 + 1], Qy = Tm[t * 7 + 2], Qz = Tm[t * 7 + 3];
  float c0 = qcoord[q * 3 + 0], c1 = qcoord[q * 3 + 1], c2 = qcoord[q * 3 + 2];
  double dr0, dr1, dr2;
  quat_rot_d((double)Qw, (double)Qx, (double)Qy, (double)Qz,
             (double)c0, (double)c1, (double)c2, dr0, dr1, dr2);
  float qr0 = (float)dr0, qr1 = (float)dr1, qr2 = (float)dr2;

  if (lane < KK) {
    s_kidx[wid][lane] = g_kidx[obase + lane];
    s_kd[wid][lane] = g_kd[obase + lane];
  }

  // rbf table: 16 k x 8 centers (wave-private LDS, no barrier)
  for (int kr = lane; kr < KK * NBB; kr += 64) {
    int k = kr >> 3, r = kr & 7;
    float d = s_kd[wid][k];
    float cc = (3.0f / 7.0f) * (float)r;
    float diff = d - cc;
    s_rbf[wid][kr] = expf(-4.0f * diff * diff);
  }

  // field[j] = gate[j] * sum_k (rbf[k,:] @ W_rbf[:,j]) * NF2[idx_k, j]
  for (int jj = 0; jj < 2; jj++) {
    int j = lane + 64 * jj;
    float wr[NBB];
#pragma unroll
    for (int r = 0; r < NBB; r++) wr[r] = W_rbf[r * DD + j];
    float acc = 0.0f;
#pragma unroll
    for (int k = 0; k < KK; k++) {
      float rw = 0.0f;
#pragma unroll
      for (int r = 0; r < NBB; r++) rw += s_rbf[wid][k * NBB + r] * wr[r];
      acc += rw * g_NF2[s_kidx[wid][k] * DD + j];
    }
    s_field[wid][j] = acc * g_gate[j];
  }

  // collapsed DTP: lane c<32 handles channel c; lin (r0..2), ang (r3..5)
  float r0 = 0, r1 = 0, r2 = 0, r3 = 0, r4 = 0, r5 = 0;
  if (lane < CHN) {
    int c = lane;
    float tF = s_field[wid][c];
    float u0 = s_field[wid][CHN + 3 * c + 0];
    float u1 = s_field[wid][CHN + 3 * c + 1];
    float u2 = s_field[wid][CHN + 3 * c + 2];
    float sc = qfeat[q * DD + c];
    float w0 = qfeat[q * DD + CHN + 3 * c + 0];
    float w1 = qfeat[q * DD + CHN + 3 * c + 1];
    float w2 = qfeat[q * DD + CHN + 3 * c + 2];
    float v0r, v1r, v2r;
    quat_rot(Qw, Qx, Qy, Qz, w0, w1, w2, v0r, v1r, v2r);
    float cx0 = v1r * u2 - v2r * u1;
    float cx1 = v2r * u0 - v0r * u2;
    float cx2 = v0r * u1 - v1r * u0;
    float Al = g_coef[c], Bl = g_coef[32 + c], Cl = g_coef[64 + c];
    float Aa = g_coef[96 + c], Ba = g_coef[128 + c], Ca = g_coef[160 + c];
    float su = Al * sc, bt = Bl * tF;
    r0 = su * u0 + bt * v0r + Cl * cx0;
    r1 = su * u1 + bt * v1r + Cl * cx1;
    r2 = su * u2 + bt * v2r + Cl * cx2;
    float sa = Aa * sc, ba = Ba * tF;
    r3 = sa * u0 + ba * v0r + Ca * cx0;
    r4 = sa * u1 + ba * v1r + Ca * cx1;
    r5 = sa * u2 + ba * v2r + Ca * cx2;
  }
#pragma unroll
  for (int off = 32; off > 0; off >>= 1) {
    r0 += __shfl_xor(r0, off, 64);
    r1 += __shfl_xor(r1, off, 64);
    r2 += __shfl_xor(r2, off, 64);
    r3 += __shfl_xor(r3, off, 64);
    r4 += __shfl_xor(r4, off, 64);
    r5 += __shfl_xor(r5, off, 64);
  }
  if (lane == 0) {
    float wq = qwgt[q];
    // orbital: cross(query_coord, R^-1 lin) = R^-1 cross(R*query_coord, lin)
    float o0 = qr1 * r2 - qr2 * r1;
    float o1 = qr2 * r0 - qr0 * r2;
    float o2 = qr0 * r1 - qr1 * r0;
    const float IA = 0.70710678118654752f;  // 1/ANG_MULT
    atomicAdd(&g_accL[t * 3 + 0], wq * r0);
    atomicAdd(&g_accL[t * 3 + 1], wq * r1);
    atomicAdd(&g_accL[t * 3 + 2], wq * r2);
    atomicAdd(&g_accA[t * 3 + 0], wq * (o0 + r3 * IA));
    atomicAdd(&g_accA[t * 3 + 1], wq * (o1 + r4 * IA));
    atomicAdd(&g_accA[t * 3 + 2], wq * (o2 + r5 * IA));
  }
}

__global__ void final_kernel(const float* __restrict__ Tm, float* __restrict__ out) {
  int t = threadIdx.x;
  if (t < NT) {
    float Qw = Tm[t * 7 + 0], Qx = -Tm[t * 7 + 1], Qy = -Tm[t * 7 + 2], Qz = -Tm[t * 7 + 3];
    float a0, a1, a2, l0, l1, l2;
    quat_rot(Qw, Qx, Qy, Qz, g_accA[t * 3 + 0], g_accA[t * 3 + 1], g_accA[t * 3 + 2], a0, a1, a2);
    quat_rot(Qw, Qx, Qy, Qz, g_accL[t * 3 + 0], g_accL[t * 3 + 1], g_accL[t * 3 + 2], l0, l1, l2);
    out[t * 3 + 0] = a0;
    out[t * 3 + 1] = a1;
    out[t * 3 + 2] = a2;
    out[NT * 3 + t * 3 + 0] = l0;
    out[NT * 3 + t * 3 + 1] = l1;
    out[NT * 3 + t * 3 + 2] = l2;
  }
}

extern "C" void kernel_launch(void* const* d_in, const int* in_sizes, int n_in,
                              void* d_out, int out_size, void* d_ws, size_t ws_size,
                              hipStream_t stream) {
  const float* T      = (const float*)d_in[0];
  const float* qwgt   = (const float*)d_in[1];
  const float* qfeat  = (const float*)d_in[2];
  const float* qcoord = (const float*)d_in[3];
  const float* nfeat  = (const float*)d_in[4];
  const float* ncoord = (const float*)d_in[5];
  const float* temb   = (const float*)d_in[6];
  const float* W_ext  = (const float*)d_in[7];
  const float* W_rbf  = (const float*)d_in[8];
  const float* W_time = (const float*)d_in[9];
  const float* wp_lin = (const float*)d_in[10];
  // d_in[11] W_scal_lin: dead ([:,1:] drops the scalar channel)
  const float* Wv_lin = (const float*)d_in[12];
  const float* wp_ang = (const float*)d_in[13];
  // d_in[14] W_scal_ang: dead
  const float* Wv_ang = (const float*)d_in[15];
  const int* qbatch   = (const int*)d_in[16];
  const int* nbatch   = (const int*)d_in[17];
  float* out = (float*)d_out;

  prep_kernel<<<513, 256, 0, stream>>>(nfeat, W_ext, nbatch, temb, W_time,
                                       wp_lin, Wv_lin, wp_ang, Wv_ang);
  select_kernel<<<512, 256, 0, stream>>>(T, qcoord, ncoord, qbatch);
  epi_kernel<<<(NT * NQ) / 4, 256, 0, stream>>>(T, qwgt, qfeat, qcoord, W_rbf);
  final_kernel<<<1, 64, 0, stream>>>(T, out);
}

// Round 11
// 166.697 us; speedup vs baseline: 1.7895x; 1.7895x over previous
//
#include <hip/hip_runtime.h>
#include <math.h>

#define NT 32
#define NQ 256
#define NN 8192
#define DD 128
#define CHN 32
#define KK 16
#define NBB 8
#define NBATCH 4
#define CAP 128   // candidate cap per (wave,t); observed ncand ~30-60
#define TFUSE 4   // t's fused per wave

// Persistent device scratch (fully rewritten every launch)
__device__ float g_NF2[NN * DD];     // node_feature @ W_ext (gate applied in main)
__device__ float g_gate[DD];
__device__ float g_coef[192];        // Al,Bl,Cl,Aa,Ba,Ca  (6 x 32)
__device__ int   g_bstart[NBATCH];
__device__ int   g_bend[NBATCH];
__device__ float g_part[NT * NQ * 6]; // per-(t,q) weighted partials [main->reduce]

__device__ __forceinline__ void quat_rot(float w, float x, float y, float z,
                                         float v0, float v1, float v2,
                                         float& r0, float& r1, float& r2) {
  float uv0 = y * v2 - z * v1;
  float uv1 = z * v0 - x * v2;
  float uv2 = x * v1 - y * v0;
  float uuv0 = y * uv2 - z * uv1;
  float uuv1 = z * uv0 - x * uv2;
  float uuv2 = x * uv1 - y * uv0;
  r0 = v0 + 2.0f * (w * uv0 + uuv0);
  r1 = v1 + 2.0f * (w * uv1 + uuv1);
  r2 = v2 + 2.0f * (w * uv2 + uuv2);
}

__device__ __forceinline__ void quat_rot_d(double w, double x, double y, double z,
                                           double v0, double v1, double v2,
                                           double& r0, double& r1, double& r2) {
  double uv0 = y * v2 - z * v1;
  double uv1 = z * v0 - x * v2;
  double uv2 = x * v1 - y * v0;
  double uuv0 = y * uv2 - z * uv1;
  double uuv1 = z * uv0 - x * uv2;
  double uuv2 = x * uv1 - y * uv0;
  r0 = v0 + 2.0 * (w * uv0 + uuv0);
  r1 = v1 + 2.0 * (w * uv1 + uuv1);
  r2 = v2 + 2.0 * (w * uv2 + uuv2);
}

// Blocks 0..511: NF2[n,j] = sum_d nf[n,d]*W_ext[d,j]  (gate applied in main)
// Block 512: setup — r3-proven write-only globals.
__global__ __launch_bounds__(256) void prep_kernel(
    const float* __restrict__ nf, const float* __restrict__ W_ext,
    const int* __restrict__ node_batch, const float* __restrict__ time_emb,
    const float* __restrict__ W_time,
    const float* __restrict__ w_path_lin, const float* __restrict__ W_vec_lin,
    const float* __restrict__ w_path_ang, const float* __restrict__ W_vec_ang) {
  int tid = threadIdx.x;
  if (blockIdx.x == 512) {
    if (tid < NBATCH) { g_bstart[tid] = 0; g_bend[tid] = 0; }
    __syncthreads();
    // node_batch sorted: contiguous segment boundaries, unique writer per batch
    for (int i = tid; i < NN; i += 256) {
      int v = node_batch[i];
      if (i == 0 || node_batch[i - 1] != v) g_bstart[v] = i;
      if (i == NN - 1 || node_batch[i + 1] != v) g_bend[v] = i + 1;
    }
    // gate[j] = 1 + (time_emb @ W_time)[j]
    if (tid < DD) {
      float g = 0.0f;
      for (int d = 0; d < DD; d++) g += time_emb[d] * W_time[d * DD + tid];
      g_gate[tid] = 1.0f + g;
    }
    // DTP collapse: [:,1:] kills scal path; mean over out-channels collapses W_vec.
    if (tid < 192) {
      int arr = tid >> 5, c = tid & 31;
      int path = (arr >= 3) ? (arr - 3) : arr;
      const float* Wv = (arr < 3) ? W_vec_lin : W_vec_ang;
      const float* wp = (arr < 3) ? w_path_lin : w_path_ang;
      float s = 0.0f;
      for (int o = 0; o < CHN; o++) s += Wv[(path * CHN + c) * CHN + o];
      g_coef[tid] = wp[(2 + path) * CHN + c] * (s * (1.0f / 32.0f));
    }
    return;
  }
  int gid = blockIdx.x * 256 + tid;
  int j = gid & (DD - 1);
  int n0 = (gid >> 7) * 8;
  n0 = __builtin_amdgcn_readfirstlane(n0);
  float acc[8] = {0, 0, 0, 0, 0, 0, 0, 0};
  const float* nfr = nf + (long)n0 * DD;
#pragma unroll 4
  for (int d = 0; d < DD; d++) {
    float w = W_ext[d * DD + j];
#pragma unroll
    for (int rr = 0; rr < 8; rr++) acc[rr] += nfr[rr * DD + d] * w;
  }
#pragma unroll
  for (int rr = 0; rr < 8; rr++) g_NF2[(n0 + rr) * DD + j] = acc[rr];
}

// r9-verbatim fused kernel (select TFUSE=4 + epilogue per t), except the
// 6 atomicAdds are replaced by plain stores to unique g_part slots —
// the 49K same-cacheline atomics were the suspected serialization floor.
__global__ __launch_bounds__(256) void main_kernel(
    const float* __restrict__ Tm,
    const float* __restrict__ qwgt,
    const float* __restrict__ qfeat,
    const float* __restrict__ qcoord,
    const float* __restrict__ ncoord,
    const float* __restrict__ W_rbf,
    const int* __restrict__ qbatch) {
  __shared__ int s_cidx[4][TFUSE][CAP];
  __shared__ float s_kd[4][KK];
  __shared__ int s_kidx[4][KK];
  __shared__ float s_rbf[4][KK * NBB];
  __shared__ float s_field[4][DD];

  int lane = threadIdx.x & 63;
  int wid = threadIdx.x >> 6;
  int w = blockIdx.x * 4 + wid;      // wave id in [0, 2048)
  int q = w >> 3;                     // [0, 256)
  int tg = w & 7;                     // [0, 8); t = tg*4 + tt

  float c0 = qcoord[q * 3 + 0], c1 = qcoord[q * 3 + 1], c2 = qcoord[q * 3 + 2];
  int b = qbatch[q];
  int sBeg = g_bstart[b], sEnd = g_bend[b];

  // fp32 transformed query points for the 4 fused t's (cast from fp64)
  float pf0[TFUSE], pf1[TFUSE], pf2[TFUSE];
#pragma unroll
  for (int tt = 0; tt < TFUSE; tt++) {
    int t = tg * TFUSE + tt;
    double dr0, dr1, dr2;
    quat_rot_d((double)Tm[t * 7 + 0], (double)Tm[t * 7 + 1],
               (double)Tm[t * 7 + 2], (double)Tm[t * 7 + 3],
               (double)c0, (double)c1, (double)c2, dr0, dr1, dr2);
    pf0[tt] = (float)(dr0 + (double)Tm[t * 7 + 4]);
    pf1[tt] = (float)(dr1 + (double)Tm[t * 7 + 5]);
    pf2[tt] = (float)(dr2 + (double)Tm[t * 7 + 6]);
  }

  // Pass A: per-lane min d2 for 4 t's, nodes loaded once, 4-way node interleave
  float lm[TFUSE];
#pragma unroll
  for (int tt = 0; tt < TFUSE; tt++) lm[tt] = 3.0e38f;
  for (int i = sBeg + lane; i < sEnd; i += 256) {
#pragma unroll
    for (int sub = 0; sub < 4; sub++) {
      int ii = i + (sub << 6);
      if (ii < sEnd) {
        float x = ncoord[3 * ii + 0];
        float y = ncoord[3 * ii + 1];
        float z = ncoord[3 * ii + 2];
#pragma unroll
        for (int tt = 0; tt < TFUSE; tt++) {
          float dx = pf0[tt] - x, dy = pf1[tt] - y, dz = pf2[tt] - z;
          lm[tt] = fminf(lm[tt], dx * dx + dy * dy + dz * dz);
        }
      }
    }
  }

  // per-t bitonic over 64 lane minima; thr = 16th smallest + slack
  float thrv[TFUSE];
#pragma unroll
  for (int tt = 0; tt < TFUSE; tt++) {
    float v = lm[tt];
#pragma unroll
    for (int k = 2; k <= 64; k <<= 1) {
#pragma unroll
      for (int j = k >> 1; j > 0; j >>= 1) {
        float o = __shfl_xor(v, j, 64);
        bool keep_min = (((lane & j) == 0) == ((lane & k) == 0));
        v = keep_min ? fminf(v, o) : fmaxf(v, o);
      }
    }
    thrv[tt] = __shfl(v, 15, 64) + 1.0e-3f;
  }

  // Pass B: fused compaction — nodes loaded once, 4 ballots per chunk
  int base[TFUSE];
#pragma unroll
  for (int tt = 0; tt < TFUSE; tt++) base[tt] = 0;
  for (int i0 = sBeg; i0 < sEnd; i0 += 64) {
    int i = i0 + lane;
    bool inb = (i < sEnd);
    float x = 0.0f, y = 0.0f, z = 0.0f;
    if (inb) {
      x = ncoord[3 * i + 0];
      y = ncoord[3 * i + 1];
      z = ncoord[3 * i + 2];
    }
#pragma unroll
    for (int tt = 0; tt < TFUSE; tt++) {
      bool pred = false;
      if (inb) {
        float dx = pf0[tt] - x, dy = pf1[tt] - y, dz = pf2[tt] - z;
        pred = (dx * dx + dy * dy + dz * dz) <= thrv[tt];
      }
      unsigned long long bal = __ballot(pred);
      int pre = __popcll(bal & ((1ull << lane) - 1ull));
      if (pred) {
        int pos = base[tt] + pre;
        if (pos < CAP) s_cidx[wid][tt][pos] = i;
      }
      base[tt] += __popcll(bal);
    }
  }

  // qfeat inputs (q-fixed, reused across t)
  float sc = 0, w0 = 0, w1 = 0, w2 = 0;
  if (lane < CHN) {
    sc = qfeat[q * DD + lane];
    w0 = qfeat[q * DD + CHN + 3 * lane + 0];
    w1 = qfeat[q * DD + CHN + 3 * lane + 1];
    w2 = qfeat[q * DD + CHN + 3 * lane + 2];
  }
  float wq = qwgt[q];

  // Per-t epilogue: exact fp64 ordering + field + DTP + per-slot store
  for (int tt = 0; tt < TFUSE; tt++) {
    int t = tg * TFUSE + tt;
    float Qw = Tm[t * 7 + 0], Qx = Tm[t * 7 + 1], Qy = Tm[t * 7 + 2], Qz = Tm[t * 7 + 3];
    float Xx = Tm[t * 7 + 4], Xy = Tm[t * 7 + 5], Xz = Tm[t * 7 + 6];
    double dr0, dr1, dr2;
    quat_rot_d((double)Qw, (double)Qx, (double)Qy, (double)Qz,
               (double)c0, (double)c1, (double)c2, dr0, dr1, dr2);
    double p0 = dr0 + (double)Xx, p1 = dr1 + (double)Xy, p2 = dr2 + (double)Xz;
    float qr0 = (float)dr0, qr1 = (float)dr1, qr2 = (float)dr2;
    int ncand = base[tt] < CAP ? base[tt] : CAP;

    // Pass C: key = (fp64 d2 bits, low 13 bits = node idx); u64 order == d2
    // order (d2>=0); near-ties break by ascending idx like top_k.
    if (ncand <= 64) {
      unsigned long long key = ~0ull;
      if (lane < ncand) {
        int idx = s_cidx[wid][tt][lane];
        double dx = p0 - (double)ncoord[3 * idx + 0];
        double dy = p1 - (double)ncoord[3 * idx + 1];
        double dz = p2 - (double)ncoord[3 * idx + 2];
        double d2 = dx * dx + dy * dy + dz * dz;
        key = (((unsigned long long)__double_as_longlong(d2)) & ~0x1FFFull) |
              (unsigned long long)idx;
      }
#pragma unroll
      for (int k = 2; k <= 64; k <<= 1) {
#pragma unroll
        for (int j = k >> 1; j > 0; j >>= 1) {
          unsigned long long o = __shfl_xor(key, j, 64);
          bool keep_min = (((lane & j) == 0) == ((lane & k) == 0));
          unsigned long long mn = o < key ? o : key;
          unsigned long long mx = o < key ? key : o;
          key = keep_min ? mn : mx;
        }
      }
      if (lane < KK) {
        double d2m = __longlong_as_double((long long)(key & ~0x1FFFull));
        s_kidx[wid][lane] = (int)(key & 0x1FFFull);
        s_kd[wid][lane] = (float)sqrt(fmax(d2m, 1.0e-12));
      }
    } else {  // rare: 64 < ncand <= 128 — serial 16-extraction over 2 key slots
      unsigned long long key[2];
#pragma unroll
      for (int s = 0; s < 2; s++) {
        int pos = lane + 64 * s;
        if (pos < ncand) {
          int idx = s_cidx[wid][tt][pos];
          double dx = p0 - (double)ncoord[3 * idx + 0];
          double dy = p1 - (double)ncoord[3 * idx + 1];
          double dz = p2 - (double)ncoord[3 * idx + 2];
          double d2 = dx * dx + dy * dy + dz * dz;
          key[s] = (((unsigned long long)__double_as_longlong(d2)) & ~0x1FFFull) |
                   (unsigned long long)idx;
        } else {
          key[s] = ~0ull;
        }
      }
      for (int r = 0; r < KK; r++) {
        unsigned long long kmin = key[0] < key[1] ? key[0] : key[1];
#pragma unroll
        for (int off = 32; off > 0; off >>= 1) {
          unsigned long long o = __shfl_xor(kmin, off, 64);
          kmin = (o < kmin) ? o : kmin;
        }
        if (lane == 0) {
          double d2m = __longlong_as_double((long long)(kmin & ~0x1FFFull));
          s_kidx[wid][r] = (int)(kmin & 0x1FFFull);
          s_kd[wid][r] = (float)sqrt(fmax(d2m, 1.0e-12));
        }
#pragma unroll
        for (int s = 0; s < 2; s++)
          if (key[s] == kmin) key[s] = ~0ull;
      }
    }

    // rbf table: 16 k x 8 centers (wave-private LDS, no barrier)
    for (int kr = lane; kr < KK * NBB; kr += 64) {
      int k = kr >> 3, r = kr & 7;
      float d = s_kd[wid][k];
      float cc = (3.0f / 7.0f) * (float)r;
      float diff = d - cc;
      s_rbf[wid][kr] = expf(-4.0f * diff * diff);
    }

    // field[j] = gate[j] * sum_k (rbf[k,:] @ W_rbf[:,j]) * NF2[idx_k, j]
    for (int jj = 0; jj < 2; jj++) {
      int j = lane + 64 * jj;
      float wr[NBB];
#pragma unroll
      for (int r = 0; r < NBB; r++) wr[r] = W_rbf[r * DD + j];
      float acc = 0.0f;
#pragma unroll
      for (int k = 0; k < KK; k++) {
        float rw = 0.0f;
#pragma unroll
        for (int r = 0; r < NBB; r++) rw += s_rbf[wid][k * NBB + r] * wr[r];
        acc += rw * g_NF2[s_kidx[wid][k] * DD + j];
      }
      s_field[wid][j] = acc * g_gate[j];
    }

    // collapsed DTP: lane c<32 handles channel c; lin (r0..2), ang (r3..5)
    float r0 = 0, r1 = 0, r2 = 0, r3 = 0, r4 = 0, r5 = 0;
    if (lane < CHN) {
      int c = lane;
      float tF = s_field[wid][c];
      float u0 = s_field[wid][CHN + 3 * c + 0];
      float u1 = s_field[wid][CHN + 3 * c + 1];
      float u2 = s_field[wid][CHN + 3 * c + 2];
      float v0r, v1r, v2r;
      quat_rot(Qw, Qx, Qy, Qz, w0, w1, w2, v0r, v1r, v2r);
      float cx0 = v1r * u2 - v2r * u1;
      float cx1 = v2r * u0 - v0r * u2;
      float cx2 = v0r * u1 - v1r * u0;
      float Al = g_coef[c], Bl = g_coef[32 + c], Cl = g_coef[64 + c];
      float Aa = g_coef[96 + c], Ba = g_coef[128 + c], Ca = g_coef[160 + c];
      float su = Al * sc, bt = Bl * tF;
      r0 = su * u0 + bt * v0r + Cl * cx0;
      r1 = su * u1 + bt * v1r + Cl * cx1;
      r2 = su * u2 + bt * v2r + Cl * cx2;
      float sa = Aa * sc, ba = Ba * tF;
      r3 = sa * u0 + ba * v0r + Ca * cx0;
      r4 = sa * u1 + ba * v1r + Ca * cx1;
      r5 = sa * u2 + ba * v2r + Ca * cx2;
    }
#pragma unroll
    for (int off = 32; off > 0; off >>= 1) {
      r0 += __shfl_xor(r0, off, 64);
      r1 += __shfl_xor(r1, off, 64);
      r2 += __shfl_xor(r2, off, 64);
      r3 += __shfl_xor(r3, off, 64);
      r4 += __shfl_xor(r4, off, 64);
      r5 += __shfl_xor(r5, off, 64);
    }
    if (lane == 0) {
      // orbital: cross(query_coord, R^-1 lin) = R^-1 cross(R*query_coord, lin)
      float o0 = qr1 * r2 - qr2 * r1;
      float o1 = qr2 * r0 - qr0 * r2;
      float o2 = qr0 * r1 - qr1 * r0;
      const float IA = 0.70710678118654752f;  // 1/ANG_MULT
      int pbase = (t * NQ + q) * 6;
      g_part[pbase + 0] = wq * r0;
      g_part[pbase + 1] = wq * r1;
      g_part[pbase + 2] = wq * r2;
      g_part[pbase + 3] = wq * (o0 + r3 * IA);
      g_part[pbase + 4] = wq * (o1 + r4 * IA);
      g_part[pbase + 5] = wq * (o2 + r5 * IA);
    }
  }
}

// One block per t: sum 256 q-partials (shuffle + LDS), rotate by q^-1, write out.
__global__ __launch_bounds__(256) void reduce_kernel(const float* __restrict__ Tm,
                                                     float* __restrict__ out) {
  __shared__ float s_sum[4][6];
  int t = blockIdx.x;
  int lane = threadIdx.x & 63;
  int wid = threadIdx.x >> 6;
  int q = threadIdx.x;
  float v[6];
#pragma unroll
  for (int c = 0; c < 6; c++) v[c] = g_part[(t * NQ + q) * 6 + c];
#pragma unroll
  for (int off = 32; off > 0; off >>= 1) {
#pragma unroll
    for (int c = 0; c < 6; c++) v[c] += __shfl_xor(v[c], off, 64);
  }
  if (lane == 0) {
#pragma unroll
    for (int c = 0; c < 6; c++) s_sum[wid][c] = v[c];
  }
  __syncthreads();
  if (threadIdx.x == 0) {
    float sL0 = 0, sL1 = 0, sL2 = 0, sA0 = 0, sA1 = 0, sA2 = 0;
#pragma unroll
    for (int ww = 0; ww < 4; ww++) {
      sL0 += s_sum[ww][0]; sL1 += s_sum[ww][1]; sL2 += s_sum[ww][2];
      sA0 += s_sum[ww][3]; sA1 += s_sum[ww][4]; sA2 += s_sum[ww][5];
    }
    float Qw = Tm[t * 7 + 0], Qx = -Tm[t * 7 + 1], Qy = -Tm[t * 7 + 2], Qz = -Tm[t * 7 + 3];
    float a0, a1, a2, l0, l1, l2;
    quat_rot(Qw, Qx, Qy, Qz, sA0, sA1, sA2, a0, a1, a2);
    quat_rot(Qw, Qx, Qy, Qz, sL0, sL1, sL2, l0, l1, l2);
    out[t * 3 + 0] = a0;
    out[t * 3 + 1] = a1;
    out[t * 3 + 2] = a2;
    out[NT * 3 + t * 3 + 0] = l0;
    out[NT * 3 + t * 3 + 1] = l1;
    out[NT * 3 + t * 3 + 2] = l2;
  }
}

extern "C" void kernel_launch(void* const* d_in, const int* in_sizes, int n_in,
                              void* d_out, int out_size, void* d_ws, size_t ws_size,
                              hipStream_t stream) {
  const float* T      = (const float*)d_in[0];
  const float* qwgt   = (const float*)d_in[1];
  const float* qfeat  = (const float*)d_in[2];
  const float* qcoord = (const float*)d_in[3];
  const float* nfeat  = (const float*)d_in[4];
  const float* ncoord = (const float*)d_in[5];
  const float* temb   = (const float*)d_in[6];
  const float* W_ext  = (const float*)d_in[7];
  const float* W_rbf  = (const float*)d_in[8];
  const float* W_time = (const float*)d_in[9];
  const float* wp_lin = (const float*)d_in[10];
  // d_in[11] W_scal_lin: dead ([:,1:] drops the scalar channel)
  const float* Wv_lin = (const float*)d_in[12];
  const float* wp_ang = (const float*)d_in[13];
  // d_in[14] W_scal_ang: dead
  const float* Wv_ang = (const float*)d_in[15];
  const int* qbatch   = (const int*)d_in[16];
  const int* nbatch   = (const int*)d_in[17];
  float* out = (float*)d_out;

  prep_kernel<<<513, 256, 0, stream>>>(nfeat, W_ext, nbatch, temb, W_time,
                                       wp_lin, Wv_lin, wp_ang, Wv_ang);
  main_kernel<<<512, 256, 0, stream>>>(T, qwgt, qfeat, qcoord, ncoord, W_rbf, qbatch);
  reduce_kernel<<<NT, 256, 0, stream>>>(T, out);
}

// Round 12
// 165.842 us; speedup vs baseline: 1.7987x; 1.0052x over previous
//
#include <hip/hip_runtime.h>
#include <math.h>

#define NT 32
#define NQ 256
#define NN 8192
#define DD 128
#define CHN 32
#define KK 16
#define NBB 8
#define NBATCH 4
#define CAP 128   // candidate cap per (wave,t); observed ncand ~30-60
#define TFUSE 4   // t's fused per selection wave

// Persistent device scratch (fully rewritten every launch)
__device__ float g_NF2[NN * DD];     // node_feature @ W_ext (gate applied in epi)
__device__ float g_gate[DD];
__device__ float g_coef[192];        // Al,Bl,Cl,Aa,Ba,Ca  (6 x 32)
__device__ int   g_bstart[NBATCH];
__device__ int   g_bend[NBATCH];
__device__ int   g_kidx[NT * NQ * KK];   // top-16 node idx per (t,q)  [select->epi]
__device__ float g_kd[NT * NQ * KK];     // top-16 distance per (t,q)  [select->epi]
__device__ float g_part[NT * NQ * 6];    // per-(t,q) weighted partials [epi->reduce]

__device__ __forceinline__ void quat_rot(float w, float x, float y, float z,
                                         float v0, float v1, float v2,
                                         float& r0, float& r1, float& r2) {
  float uv0 = y * v2 - z * v1;
  float uv1 = z * v0 - x * v2;
  float uv2 = x * v1 - y * v0;
  float uuv0 = y * uv2 - z * uv1;
  float uuv1 = z * uv0 - x * uv2;
  float uuv2 = x * uv1 - y * uv0;
  r0 = v0 + 2.0f * (w * uv0 + uuv0);
  r1 = v1 + 2.0f * (w * uv1 + uuv1);
  r2 = v2 + 2.0f * (w * uv2 + uuv2);
}

__device__ __forceinline__ void quat_rot_d(double w, double x, double y, double z,
                                           double v0, double v1, double v2,
                                           double& r0, double& r1, double& r2) {
  double uv0 = y * v2 - z * v1;
  double uv1 = z * v0 - x * v2;
  double uv2 = x * v1 - y * v0;
  double uuv0 = y * uv2 - z * uv1;
  double uuv1 = z * uv0 - x * uv2;
  double uuv2 = x * uv1 - y * uv0;
  r0 = v0 + 2.0 * (w * uv0 + uuv0);
  r1 = v1 + 2.0 * (w * uv1 + uuv1);
  r2 = v2 + 2.0 * (w * uv2 + uuv2);
}

// Blocks 0..511: NF2[n,j] = sum_d nf[n,d]*W_ext[d,j]  (gate applied in epi)
// Block 512: setup — r3-proven write-only globals.
__global__ __launch_bounds__(256) void prep_kernel(
    const float* __restrict__ nf, const float* __restrict__ W_ext,
    const int* __restrict__ node_batch, const float* __restrict__ time_emb,
    const float* __restrict__ W_time,
    const float* __restrict__ w_path_lin, const float* __restrict__ W_vec_lin,
    const float* __restrict__ w_path_ang, const float* __restrict__ W_vec_ang) {
  int tid = threadIdx.x;
  if (blockIdx.x == 512) {
    if (tid < NBATCH) { g_bstart[tid] = 0; g_bend[tid] = 0; }
    __syncthreads();
    // node_batch sorted: contiguous segment boundaries, unique writer per batch
    for (int i = tid; i < NN; i += 256) {
      int v = node_batch[i];
      if (i == 0 || node_batch[i - 1] != v) g_bstart[v] = i;
      if (i == NN - 1 || node_batch[i + 1] != v) g_bend[v] = i + 1;
    }
    // gate[j] = 1 + (time_emb @ W_time)[j]
    if (tid < DD) {
      float g = 0.0f;
      for (int d = 0; d < DD; d++) g += time_emb[d] * W_time[d * DD + tid];
      g_gate[tid] = 1.0f + g;
    }
    // DTP collapse: [:,1:] kills scal path; mean over out-channels collapses W_vec.
    if (tid < 192) {
      int arr = tid >> 5, c = tid & 31;
      int path = (arr >= 3) ? (arr - 3) : arr;
      const float* Wv = (arr < 3) ? W_vec_lin : W_vec_ang;
      const float* wp = (arr < 3) ? w_path_lin : w_path_ang;
      float s = 0.0f;
      for (int o = 0; o < CHN; o++) s += Wv[(path * CHN + c) * CHN + o];
      g_coef[tid] = wp[(2 + path) * CHN + c] * (s * (1.0f / 32.0f));
    }
    return;
  }
  int gid = blockIdx.x * 256 + tid;
  int j = gid & (DD - 1);
  int n0 = (gid >> 7) * 8;
  n0 = __builtin_amdgcn_readfirstlane(n0);
  float acc[8] = {0, 0, 0, 0, 0, 0, 0, 0};
  const float* nfr = nf + (long)n0 * DD;
#pragma unroll 4
  for (int d = 0; d < DD; d++) {
    float w = W_ext[d * DD + j];
#pragma unroll
    for (int rr = 0; rr < 8; rr++) acc[rr] += nfr[rr * DD + d] * w;
  }
#pragma unroll
  for (int rr = 0; rr < 8; rr++) g_NF2[(n0 + rr) * DD + j] = acc[rr];
}

// Selection only (r10-verbatim, passed): one wave per (q, tg), TFUSE=4 t's
// fused; writes exact top-16 (idx, d) per (t,q) to global scratch.
__global__ __launch_bounds__(256) void select_kernel(
    const float* __restrict__ Tm,
    const float* __restrict__ qcoord,
    const float* __restrict__ ncoord,
    const int* __restrict__ qbatch) {
  __shared__ int s_cidx[4][TFUSE][CAP];

  int lane = threadIdx.x & 63;
  int wid = threadIdx.x >> 6;
  int w = blockIdx.x * 4 + wid;      // wave id in [0, 2048)
  int q = w >> 3;                     // [0, 256)
  int tg = w & 7;                     // [0, 8); t = tg*4 + tt

  float c0 = qcoord[q * 3 + 0], c1 = qcoord[q * 3 + 1], c2 = qcoord[q * 3 + 2];
  int b = qbatch[q];
  int sBeg = g_bstart[b], sEnd = g_bend[b];

  // fp32 transformed query points for the 4 fused t's (cast from fp64)
  float pf0[TFUSE], pf1[TFUSE], pf2[TFUSE];
#pragma unroll
  for (int tt = 0; tt < TFUSE; tt++) {
    int t = tg * TFUSE + tt;
    double dr0, dr1, dr2;
    quat_rot_d((double)Tm[t * 7 + 0], (double)Tm[t * 7 + 1],
               (double)Tm[t * 7 + 2], (double)Tm[t * 7 + 3],
               (double)c0, (double)c1, (double)c2, dr0, dr1, dr2);
    pf0[tt] = (float)(dr0 + (double)Tm[t * 7 + 4]);
    pf1[tt] = (float)(dr1 + (double)Tm[t * 7 + 5]);
    pf2[tt] = (float)(dr2 + (double)Tm[t * 7 + 6]);
  }

  // Pass A: per-lane min d2 for 4 t's, nodes loaded once, 4-way node interleave
  float lm[TFUSE];
#pragma unroll
  for (int tt = 0; tt < TFUSE; tt++) lm[tt] = 3.0e38f;
  for (int i = sBeg + lane; i < sEnd; i += 256) {
#pragma unroll
    for (int sub = 0; sub < 4; sub++) {
      int ii = i + (sub << 6);
      if (ii < sEnd) {
        float x = ncoord[3 * ii + 0];
        float y = ncoord[3 * ii + 1];
        float z = ncoord[3 * ii + 2];
#pragma unroll
        for (int tt = 0; tt < TFUSE; tt++) {
          float dx = pf0[tt] - x, dy = pf1[tt] - y, dz = pf2[tt] - z;
          lm[tt] = fminf(lm[tt], dx * dx + dy * dy + dz * dz);
        }
      }
    }
  }

  // per-t bitonic over 64 lane minima; thr = 16th smallest + slack
  float thrv[TFUSE];
#pragma unroll
  for (int tt = 0; tt < TFUSE; tt++) {
    float v = lm[tt];
#pragma unroll
    for (int k = 2; k <= 64; k <<= 1) {
#pragma unroll
      for (int j = k >> 1; j > 0; j >>= 1) {
        float o = __shfl_xor(v, j, 64);
        bool keep_min = (((lane & j) == 0) == ((lane & k) == 0));
        v = keep_min ? fminf(v, o) : fmaxf(v, o);
      }
    }
    thrv[tt] = __shfl(v, 15, 64) + 1.0e-3f;
  }

  // Pass B: fused compaction — nodes loaded once, 4 ballots per chunk
  int base[TFUSE];
#pragma unroll
  for (int tt = 0; tt < TFUSE; tt++) base[tt] = 0;
  for (int i0 = sBeg; i0 < sEnd; i0 += 64) {
    int i = i0 + lane;
    bool inb = (i < sEnd);
    float x = 0.0f, y = 0.0f, z = 0.0f;
    if (inb) {
      x = ncoord[3 * i + 0];
      y = ncoord[3 * i + 1];
      z = ncoord[3 * i + 2];
    }
#pragma unroll
    for (int tt = 0; tt < TFUSE; tt++) {
      bool pred = false;
      if (inb) {
        float dx = pf0[tt] - x, dy = pf1[tt] - y, dz = pf2[tt] - z;
        pred = (dx * dx + dy * dy + dz * dz) <= thrv[tt];
      }
      unsigned long long bal = __ballot(pred);
      int pre = __popcll(bal & ((1ull << lane) - 1ull));
      if (pred) {
        int pos = base[tt] + pre;
        if (pos < CAP) s_cidx[wid][tt][pos] = i;
      }
      base[tt] += __popcll(bal);
    }
  }

  // Pass C per t: exact fp64 ordering; write top-16 (idx, d) to global.
  for (int tt = 0; tt < TFUSE; tt++) {
    int t = tg * TFUSE + tt;
    double dr0, dr1, dr2;
    quat_rot_d((double)Tm[t * 7 + 0], (double)Tm[t * 7 + 1],
               (double)Tm[t * 7 + 2], (double)Tm[t * 7 + 3],
               (double)c0, (double)c1, (double)c2, dr0, dr1, dr2);
    double p0 = dr0 + (double)Tm[t * 7 + 4];
    double p1 = dr1 + (double)Tm[t * 7 + 5];
    double p2 = dr2 + (double)Tm[t * 7 + 6];
    int ncand = base[tt] < CAP ? base[tt] : CAP;
    int obase = (t * NQ + q) * KK;

    if (ncand <= 64) {
      unsigned long long key = ~0ull;
      if (lane < ncand) {
        int idx = s_cidx[wid][tt][lane];
        double dx = p0 - (double)ncoord[3 * idx + 0];
        double dy = p1 - (double)ncoord[3 * idx + 1];
        double dz = p2 - (double)ncoord[3 * idx + 2];
        double d2 = dx * dx + dy * dy + dz * dz;
        key = (((unsigned long long)__double_as_longlong(d2)) & ~0x1FFFull) |
              (unsigned long long)idx;
      }
#pragma unroll
      for (int k = 2; k <= 64; k <<= 1) {
#pragma unroll
        for (int j = k >> 1; j > 0; j >>= 1) {
          unsigned long long o = __shfl_xor(key, j, 64);
          bool keep_min = (((lane & j) == 0) == ((lane & k) == 0));
          unsigned long long mn = o < key ? o : key;
          unsigned long long mx = o < key ? key : o;
          key = keep_min ? mn : mx;
        }
      }
      if (lane < KK) {
        double d2m = __longlong_as_double((long long)(key & ~0x1FFFull));
        g_kidx[obase + lane] = (int)(key & 0x1FFFull);
        g_kd[obase + lane] = (float)sqrt(fmax(d2m, 1.0e-12));
      }
    } else {  // rare: 64 < ncand <= 128 — serial 16-extraction over 2 key slots
      unsigned long long key[2];
#pragma unroll
      for (int s = 0; s < 2; s++) {
        int pos = lane + 64 * s;
        if (pos < ncand) {
          int idx = s_cidx[wid][tt][pos];
          double dx = p0 - (double)ncoord[3 * idx + 0];
          double dy = p1 - (double)ncoord[3 * idx + 1];
          double dz = p2 - (double)ncoord[3 * idx + 2];
          double d2 = dx * dx + dy * dy + dz * dz;
          key[s] = (((unsigned long long)__double_as_longlong(d2)) & ~0x1FFFull) |
                   (unsigned long long)idx;
        } else {
          key[s] = ~0ull;
        }
      }
      for (int r = 0; r < KK; r++) {
        unsigned long long kmin = key[0] < key[1] ? key[0] : key[1];
#pragma unroll
        for (int off = 32; off > 0; off >>= 1) {
          unsigned long long o = __shfl_xor(kmin, off, 64);
          kmin = (o < kmin) ? o : kmin;
        }
        if (lane == 0) {
          double d2m = __longlong_as_double((long long)(kmin & ~0x1FFFull));
          g_kidx[obase + r] = (int)(kmin & 0x1FFFull);
          g_kd[obase + r] = (float)sqrt(fmax(d2m, 1.0e-12));
        }
#pragma unroll
        for (int s = 0; s < 2; s++)
          if (key[s] == kmin) key[s] = ~0ull;
      }
    }
  }
}

// Epilogue: one wave per (t,q) — 8192 waves (32/CU full occupancy) to hide the
// scattered NF2 loads and LDS chains. r10-verbatim except the output atomics
// are replaced by plain stores to unique g_part slots (the r11-proven fix).
__global__ __launch_bounds__(256) void epi_kernel(
    const float* __restrict__ Tm,
    const float* __restrict__ qwgt,
    const float* __restrict__ qfeat,
    const float* __restrict__ qcoord,
    const float* __restrict__ W_rbf) {
  __shared__ float s_kd[4][KK];
  __shared__ int s_kidx[4][KK];
  __shared__ float s_rbf[4][KK * NBB];
  __shared__ float s_field[4][DD];

  int lane = threadIdx.x & 63;
  int wid = threadIdx.x >> 6;
  int m = blockIdx.x * 4 + wid;
  int t = m >> 8, q = m & (NQ - 1);
  int obase = m * KK;  // m == t*NQ + q

  float Qw = Tm[t * 7 + 0], Qx = Tm[t * 7 + 1], Qy = Tm[t * 7 + 2], Qz = Tm[t * 7 + 3];
  float c0 = qcoord[q * 3 + 0], c1 = qcoord[q * 3 + 1], c2 = qcoord[q * 3 + 2];
  double dr0, dr1, dr2;
  quat_rot_d((double)Qw, (double)Qx, (double)Qy, (double)Qz,
             (double)c0, (double)c1, (double)c2, dr0, dr1, dr2);
  float qr0 = (float)dr0, qr1 = (float)dr1, qr2 = (float)dr2;

  if (lane < KK) {
    s_kidx[wid][lane] = g_kidx[obase + lane];
    s_kd[wid][lane] = g_kd[obase + lane];
  }

  // rbf table: 16 k x 8 centers (wave-private LDS, no barrier)
  for (int kr = lane; kr < KK * NBB; kr += 64) {
    int k = kr >> 3, r = kr & 7;
    float d = s_kd[wid][k];
    float cc = (3.0f / 7.0f) * (float)r;
    float diff = d - cc;
    s_rbf[wid][kr] = expf(-4.0f * diff * diff);
  }

  // field[j] = gate[j] * sum_k (rbf[k,:] @ W_rbf[:,j]) * NF2[idx_k, j]
  for (int jj = 0; jj < 2; jj++) {
    int j = lane + 64 * jj;
    float wr[NBB];
#pragma unroll
    for (int r = 0; r < NBB; r++) wr[r] = W_rbf[r * DD + j];
    float acc = 0.0f;
#pragma unroll
    for (int k = 0; k < KK; k++) {
      float rw = 0.0f;
#pragma unroll
      for (int r = 0; r < NBB; r++) rw += s_rbf[wid][k * NBB + r] * wr[r];
      acc += rw * g_NF2[s_kidx[wid][k] * DD + j];
    }
    s_field[wid][j] = acc * g_gate[j];
  }

  // collapsed DTP: lane c<32 handles channel c; lin (r0..2), ang (r3..5)
  float r0 = 0, r1 = 0, r2 = 0, r3 = 0, r4 = 0, r5 = 0;
  if (lane < CHN) {
    int c = lane;
    float tF = s_field[wid][c];
    float u0 = s_field[wid][CHN + 3 * c + 0];
    float u1 = s_field[wid][CHN + 3 * c + 1];
    float u2 = s_field[wid][CHN + 3 * c + 2];
    float sc = qfeat[q * DD + c];
    float w0 = qfeat[q * DD + CHN + 3 * c + 0];
    float w1 = qfeat[q * DD + CHN + 3 * c + 1];
    float w2 = qfeat[q * DD + CHN + 3 * c + 2];
    float v0r, v1r, v2r;
    quat_rot(Qw, Qx, Qy, Qz, w0, w1, w2, v0r, v1r, v2r);
    float cx0 = v1r * u2 - v2r * u1;
    float cx1 = v2r * u0 - v0r * u2;
    float cx2 = v0r * u1 - v1r * u0;
    float Al = g_coef[c], Bl = g_coef[32 + c], Cl = g_coef[64 + c];
    float Aa = g_coef[96 + c], Ba = g_coef[128 + c], Ca = g_coef[160 + c];
    float su = Al * sc, bt = Bl * tF;
    r0 = su * u0 + bt * v0r + Cl * cx0;
    r1 = su * u1 + bt * v1r + Cl * cx1;
    r2 = su * u2 + bt * v2r + Cl * cx2;
    float sa = Aa * sc, ba = Ba * tF;
    r3 = sa * u0 + ba * v0r + Ca * cx0;
    r4 = sa * u1 + ba * v1r + Ca * cx1;
    r5 = sa * u2 + ba * v2r + Ca * cx2;
  }
#pragma unroll
  for (int off = 32; off > 0; off >>= 1) {
    r0 += __shfl_xor(r0, off, 64);
    r1 += __shfl_xor(r1, off, 64);
    r2 += __shfl_xor(r2, off, 64);
    r3 += __shfl_xor(r3, off, 64);
    r4 += __shfl_xor(r4, off, 64);
    r5 += __shfl_xor(r5, off, 64);
  }
  if (lane == 0) {
    float wq = qwgt[q];
    // orbital: cross(query_coord, R^-1 lin) = R^-1 cross(R*query_coord, lin)
    float o0 = qr1 * r2 - qr2 * r1;
    float o1 = qr2 * r0 - qr0 * r2;
    float o2 = qr0 * r1 - qr1 * r0;
    const float IA = 0.70710678118654752f;  // 1/ANG_MULT
    int pbase = m * 6;
    g_part[pbase + 0] = wq * r0;
    g_part[pbase + 1] = wq * r1;
    g_part[pbase + 2] = wq * r2;
    g_part[pbase + 3] = wq * (o0 + r3 * IA);
    g_part[pbase + 4] = wq * (o1 + r4 * IA);
    g_part[pbase + 5] = wq * (o2 + r5 * IA);
  }
}

// One block per t: sum 256 q-partials (shuffle + LDS), rotate by q^-1, write out.
__global__ __launch_bounds__(256) void reduce_kernel(const float* __restrict__ Tm,
                                                     float* __restrict__ out) {
  __shared__ float s_sum[4][6];
  int t = blockIdx.x;
  int lane = threadIdx.x & 63;
  int wid = threadIdx.x >> 6;
  int q = threadIdx.x;
  float v[6];
#pragma unroll
  for (int c = 0; c < 6; c++) v[c] = g_part[(t * NQ + q) * 6 + c];
#pragma unroll
  for (int off = 32; off > 0; off >>= 1) {
#pragma unroll
    for (int c = 0; c < 6; c++) v[c] += __shfl_xor(v[c], off, 64);
  }
  if (lane == 0) {
#pragma unroll
    for (int c = 0; c < 6; c++) s_sum[wid][c] = v[c];
  }
  __syncthreads();
  if (threadIdx.x == 0) {
    float sL0 = 0, sL1 = 0, sL2 = 0, sA0 = 0, sA1 = 0, sA2 = 0;
#pragma unroll
    for (int ww = 0; ww < 4; ww++) {
      sL0 += s_sum[ww][0]; sL1 += s_sum[ww][1]; sL2 += s_sum[ww][2];
      sA0 += s_sum[ww][3]; sA1 += s_sum[ww][4]; sA2 += s_sum[ww][5];
    }
    float Qw = Tm[t * 7 + 0], Qx = -Tm[t * 7 + 1], Qy = -Tm[t * 7 + 2], Qz = -Tm[t * 7 + 3];
    float a0, a1, a2, l0, l1, l2;
    quat_rot(Qw, Qx, Qy, Qz, sA0, sA1, sA2, a0, a1, a2);
    quat_rot(Qw, Qx, Qy, Qz, sL0, sL1, sL2, l0, l1, l2);
    out[t * 3 + 0] = a0;
    out[t * 3 + 1] = a1;
    out[t * 3 + 2] = a2;
    out[NT * 3 + t * 3 + 0] = l0;
    out[NT * 3 + t * 3 + 1] = l1;
    out[NT * 3 + t * 3 + 2] = l2;
  }
}

extern "C" void kernel_launch(void* const* d_in, const int* in_sizes, int n_in,
                              void* d_out, int out_size, void* d_ws, size_t ws_size,
                              hipStream_t stream) {
  const float* T      = (const float*)d_in[0];
  const float* qwgt   = (const float*)d_in[1];
  const float* qfeat  = (const float*)d_in[2];
  const float* qcoord = (const float*)d_in[3];
  const float* nfeat  = (const float*)d_in[4];
  const float* ncoord = (const float*)d_in[5];
  const float* temb   = (const float*)d_in[6];
  const float* W_ext  = (const float*)d_in[7];
  const float* W_rbf  = (const float*)d_in[8];
  const float* W_time = (const float*)d_in[9];
  const float* wp_lin = (const float*)d_in[10];
  // d_in[11] W_scal_lin: dead ([:,1:] drops the scalar channel)
  const float* Wv_lin = (const float*)d_in[12];
  const float* wp_ang = (const float*)d_in[13];
  // d_in[14] W_scal_ang: dead
  const float* Wv_ang = (const float*)d_in[15];
  const int* qbatch   = (const int*)d_in[16];
  const int* nbatch   = (const int*)d_in[17];
  float* out = (float*)d_out;

  prep_kernel<<<513, 256, 0, stream>>>(nfeat, W_ext, nbatch, temb, W_time,
                                       wp_lin, Wv_lin, wp_ang, Wv_ang);
  select_kernel<<<512, 256, 0, stream>>>(T, qcoord, ncoord, qbatch);
  epi_kernel<<<(NT * NQ) / 4, 256, 0, stream>>>(T, qwgt, qfeat, qcoord, W_rbf);
  reduce_kernel<<<NT, 256, 0, stream>>>(T, out);
}

// Round 13
// 155.902 us; speedup vs baseline: 1.9134x; 1.0638x over previous
//
#include <hip/hip_runtime.h>
#include <math.h>

#define NT 32
#define NQ 256
#define NN 8192
#define DD 128
#define CHN 32
#define KK 16
#define NBB 8
#define NBATCH 4
#define CAP 128   // candidate cap per (wave,t); observed ncand ~30-60
#define TFUSE 2   // t's fused per selection wave (r13: 4->2 for 2x wave parallelism)
#define NTG (NT / TFUSE)   // 16 t-groups per q

// Persistent device scratch (fully rewritten every launch)
__device__ float g_NF2[NN * DD];     // node_feature @ W_ext (gate applied in epi)
__device__ float g_gate[DD];
__device__ float g_coef[192];        // Al,Bl,Cl,Aa,Ba,Ca  (6 x 32)
__device__ int   g_bstart[NBATCH];
__device__ int   g_bend[NBATCH];
__device__ int   g_kidx[NT * NQ * KK];   // top-16 node idx per (t,q)  [select->epi]
__device__ float g_kd[NT * NQ * KK];     // top-16 distance per (t,q)  [select->epi]
__device__ float g_part[NT * NQ * 6];    // per-(t,q) weighted partials [epi->reduce]

__device__ __forceinline__ void quat_rot(float w, float x, float y, float z,
                                         float v0, float v1, float v2,
                                         float& r0, float& r1, float& r2) {
  float uv0 = y * v2 - z * v1;
  float uv1 = z * v0 - x * v2;
  float uv2 = x * v1 - y * v0;
  float uuv0 = y * uv2 - z * uv1;
  float uuv1 = z * uv0 - x * uv2;
  float uuv2 = x * uv1 - y * uv0;
  r0 = v0 + 2.0f * (w * uv0 + uuv0);
  r1 = v1 + 2.0f * (w * uv1 + uuv1);
  r2 = v2 + 2.0f * (w * uv2 + uuv2);
}

__device__ __forceinline__ void quat_rot_d(double w, double x, double y, double z,
                                           double v0, double v1, double v2,
                                           double& r0, double& r1, double& r2) {
  double uv0 = y * v2 - z * v1;
  double uv1 = z * v0 - x * v2;
  double uv2 = x * v1 - y * v0;
  double uuv0 = y * uv2 - z * uv1;
  double uuv1 = z * uv0 - x * uv2;
  double uuv2 = x * uv1 - y * uv0;
  r0 = v0 + 2.0 * (w * uv0 + uuv0);
  r1 = v1 + 2.0 * (w * uv1 + uuv1);
  r2 = v2 + 2.0 * (w * uv2 + uuv2);
}

// Blocks 0..511: NF2[n,j] = sum_d nf[n,d]*W_ext[d,j]  (gate applied in epi)
// Block 512: setup — r3-proven write-only globals.
__global__ __launch_bounds__(256) void prep_kernel(
    const float* __restrict__ nf, const float* __restrict__ W_ext,
    const int* __restrict__ node_batch, const float* __restrict__ time_emb,
    const float* __restrict__ W_time,
    const float* __restrict__ w_path_lin, const float* __restrict__ W_vec_lin,
    const float* __restrict__ w_path_ang, const float* __restrict__ W_vec_ang) {
  int tid = threadIdx.x;
  if (blockIdx.x == 512) {
    if (tid < NBATCH) { g_bstart[tid] = 0; g_bend[tid] = 0; }
    __syncthreads();
    // node_batch sorted: contiguous segment boundaries, unique writer per batch
    for (int i = tid; i < NN; i += 256) {
      int v = node_batch[i];
      if (i == 0 || node_batch[i - 1] != v) g_bstart[v] = i;
      if (i == NN - 1 || node_batch[i + 1] != v) g_bend[v] = i + 1;
    }
    // gate[j] = 1 + (time_emb @ W_time)[j]
    if (tid < DD) {
      float g = 0.0f;
      for (int d = 0; d < DD; d++) g += time_emb[d] * W_time[d * DD + tid];
      g_gate[tid] = 1.0f + g;
    }
    // DTP collapse: [:,1:] kills scal path; mean over out-channels collapses W_vec.
    if (tid < 192) {
      int arr = tid >> 5, c = tid & 31;
      int path = (arr >= 3) ? (arr - 3) : arr;
      const float* Wv = (arr < 3) ? W_vec_lin : W_vec_ang;
      const float* wp = (arr < 3) ? w_path_lin : w_path_ang;
      float s = 0.0f;
      for (int o = 0; o < CHN; o++) s += Wv[(path * CHN + c) * CHN + o];
      g_coef[tid] = wp[(2 + path) * CHN + c] * (s * (1.0f / 32.0f));
    }
    return;
  }
  int gid = blockIdx.x * 256 + tid;
  int j = gid & (DD - 1);
  int n0 = (gid >> 7) * 8;
  n0 = __builtin_amdgcn_readfirstlane(n0);
  float acc[8] = {0, 0, 0, 0, 0, 0, 0, 0};
  const float* nfr = nf + (long)n0 * DD;
#pragma unroll 4
  for (int d = 0; d < DD; d++) {
    float w = W_ext[d * DD + j];
#pragma unroll
    for (int rr = 0; rr < 8; rr++) acc[rr] += nfr[rr * DD + d] * w;
  }
#pragma unroll
  for (int rr = 0; rr < 8; rr++) g_NF2[(n0 + rr) * DD + j] = acc[rr];
}

// Selection (r12-verbatim flow, TFUSE=2): one wave per (q, tg); writes exact
// top-16 (idx, d) per (t,q) to global scratch. Per-(t,q) selection values are
// bit-identical to r12: node partition, fp32 minima, thresholds, candidate
// sets, and fp64 keys are all independent of TFUSE.
__global__ __launch_bounds__(256) void select_kernel(
    const float* __restrict__ Tm,
    const float* __restrict__ qcoord,
    const float* __restrict__ ncoord,
    const int* __restrict__ qbatch) {
  __shared__ int s_cidx[4][TFUSE][CAP];

  int lane = threadIdx.x & 63;
  int wid = threadIdx.x >> 6;
  int w = blockIdx.x * 4 + wid;      // wave id in [0, 4096)
  int q = w >> 4;                     // [0, 256)
  int tg = w & (NTG - 1);             // [0, 16); t = tg*2 + tt

  float c0 = qcoord[q * 3 + 0], c1 = qcoord[q * 3 + 1], c2 = qcoord[q * 3 + 2];
  int b = qbatch[q];
  int sBeg = g_bstart[b], sEnd = g_bend[b];

  // fp32 transformed query points for the fused t's (cast from fp64)
  float pf0[TFUSE], pf1[TFUSE], pf2[TFUSE];
#pragma unroll
  for (int tt = 0; tt < TFUSE; tt++) {
    int t = tg * TFUSE + tt;
    double dr0, dr1, dr2;
    quat_rot_d((double)Tm[t * 7 + 0], (double)Tm[t * 7 + 1],
               (double)Tm[t * 7 + 2], (double)Tm[t * 7 + 3],
               (double)c0, (double)c1, (double)c2, dr0, dr1, dr2);
    pf0[tt] = (float)(dr0 + (double)Tm[t * 7 + 4]);
    pf1[tt] = (float)(dr1 + (double)Tm[t * 7 + 5]);
    pf2[tt] = (float)(dr2 + (double)Tm[t * 7 + 6]);
  }

  // Pass A: per-lane min d2 per t, nodes loaded once, 4-way node interleave
  float lm[TFUSE];
#pragma unroll
  for (int tt = 0; tt < TFUSE; tt++) lm[tt] = 3.0e38f;
  for (int i = sBeg + lane; i < sEnd; i += 256) {
#pragma unroll
    for (int sub = 0; sub < 4; sub++) {
      int ii = i + (sub << 6);
      if (ii < sEnd) {
        float x = ncoord[3 * ii + 0];
        float y = ncoord[3 * ii + 1];
        float z = ncoord[3 * ii + 2];
#pragma unroll
        for (int tt = 0; tt < TFUSE; tt++) {
          float dx = pf0[tt] - x, dy = pf1[tt] - y, dz = pf2[tt] - z;
          lm[tt] = fminf(lm[tt], dx * dx + dy * dy + dz * dz);
        }
      }
    }
  }

  // per-t bitonic over 64 lane minima; thr = 16th smallest + slack
  float thrv[TFUSE];
#pragma unroll
  for (int tt = 0; tt < TFUSE; tt++) {
    float v = lm[tt];
#pragma unroll
    for (int k = 2; k <= 64; k <<= 1) {
#pragma unroll
      for (int j = k >> 1; j > 0; j >>= 1) {
        float o = __shfl_xor(v, j, 64);
        bool keep_min = (((lane & j) == 0) == ((lane & k) == 0));
        v = keep_min ? fminf(v, o) : fmaxf(v, o);
      }
    }
    thrv[tt] = __shfl(v, 15, 64) + 1.0e-3f;
  }

  // Pass B: fused compaction — nodes loaded once, TFUSE ballots per chunk
  int base[TFUSE];
#pragma unroll
  for (int tt = 0; tt < TFUSE; tt++) base[tt] = 0;
  for (int i0 = sBeg; i0 < sEnd; i0 += 64) {
    int i = i0 + lane;
    bool inb = (i < sEnd);
    float x = 0.0f, y = 0.0f, z = 0.0f;
    if (inb) {
      x = ncoord[3 * i + 0];
      y = ncoord[3 * i + 1];
      z = ncoord[3 * i + 2];
    }
#pragma unroll
    for (int tt = 0; tt < TFUSE; tt++) {
      bool pred = false;
      if (inb) {
        float dx = pf0[tt] - x, dy = pf1[tt] - y, dz = pf2[tt] - z;
        pred = (dx * dx + dy * dy + dz * dz) <= thrv[tt];
      }
      unsigned long long bal = __ballot(pred);
      int pre = __popcll(bal & ((1ull << lane) - 1ull));
      if (pred) {
        int pos = base[tt] + pre;
        if (pos < CAP) s_cidx[wid][tt][pos] = i;
      }
      base[tt] += __popcll(bal);
    }
  }

  // Pass C per t: exact fp64 ordering; write top-16 (idx, d) to global.
  for (int tt = 0; tt < TFUSE; tt++) {
    int t = tg * TFUSE + tt;
    double dr0, dr1, dr2;
    quat_rot_d((double)Tm[t * 7 + 0], (double)Tm[t * 7 + 1],
               (double)Tm[t * 7 + 2], (double)Tm[t * 7 + 3],
               (double)c0, (double)c1, (double)c2, dr0, dr1, dr2);
    double p0 = dr0 + (double)Tm[t * 7 + 4];
    double p1 = dr1 + (double)Tm[t * 7 + 5];
    double p2 = dr2 + (double)Tm[t * 7 + 6];
    int ncand = base[tt] < CAP ? base[tt] : CAP;
    int obase = (t * NQ + q) * KK;

    if (ncand <= 64) {
      unsigned long long key = ~0ull;
      if (lane < ncand) {
        int idx = s_cidx[wid][tt][lane];
        double dx = p0 - (double)ncoord[3 * idx + 0];
        double dy = p1 - (double)ncoord[3 * idx + 1];
        double dz = p2 - (double)ncoord[3 * idx + 2];
        double d2 = dx * dx + dy * dy + dz * dz;
        key = (((unsigned long long)__double_as_longlong(d2)) & ~0x1FFFull) |
              (unsigned long long)idx;
      }
#pragma unroll
      for (int k = 2; k <= 64; k <<= 1) {
#pragma unroll
        for (int j = k >> 1; j > 0; j >>= 1) {
          unsigned long long o = __shfl_xor(key, j, 64);
          bool keep_min = (((lane & j) == 0) == ((lane & k) == 0));
          unsigned long long mn = o < key ? o : key;
          unsigned long long mx = o < key ? key : o;
          key = keep_min ? mn : mx;
        }
      }
      if (lane < KK) {
        double d2m = __longlong_as_double((long long)(key & ~0x1FFFull));
        g_kidx[obase + lane] = (int)(key & 0x1FFFull);
        g_kd[obase + lane] = (float)sqrt(fmax(d2m, 1.0e-12));
      }
    } else {  // rare: 64 < ncand <= 128 — serial 16-extraction over 2 key slots
      unsigned long long key[2];
#pragma unroll
      for (int s = 0; s < 2; s++) {
        int pos = lane + 64 * s;
        if (pos < ncand) {
          int idx = s_cidx[wid][tt][pos];
          double dx = p0 - (double)ncoord[3 * idx + 0];
          double dy = p1 - (double)ncoord[3 * idx + 1];
          double dz = p2 - (double)ncoord[3 * idx + 2];
          double d2 = dx * dx + dy * dy + dz * dz;
          key[s] = (((unsigned long long)__double_as_longlong(d2)) & ~0x1FFFull) |
                   (unsigned long long)idx;
        } else {
          key[s] = ~0ull;
        }
      }
      for (int r = 0; r < KK; r++) {
        unsigned long long kmin = key[0] < key[1] ? key[0] : key[1];
#pragma unroll
        for (int off = 32; off > 0; off >>= 1) {
          unsigned long long o = __shfl_xor(kmin, off, 64);
          kmin = (o < kmin) ? o : kmin;
        }
        if (lane == 0) {
          double d2m = __longlong_as_double((long long)(kmin & ~0x1FFFull));
          g_kidx[obase + r] = (int)(kmin & 0x1FFFull);
          g_kd[obase + r] = (float)sqrt(fmax(d2m, 1.0e-12));
        }
#pragma unroll
        for (int s = 0; s < 2; s++)
          if (key[s] == kmin) key[s] = ~0ull;
      }
    }
  }
}

// Epilogue: one wave per (t,q) — 8192 waves (full occupancy). r12-verbatim.
__global__ __launch_bounds__(256) void epi_kernel(
    const float* __restrict__ Tm,
    const float* __restrict__ qwgt,
    const float* __restrict__ qfeat,
    const float* __restrict__ qcoord,
    const float* __restrict__ W_rbf) {
  __shared__ float s_kd[4][KK];
  __shared__ int s_kidx[4][KK];
  __shared__ float s_rbf[4][KK * NBB];
  __shared__ float s_field[4][DD];

  int lane = threadIdx.x & 63;
  int wid = threadIdx.x >> 6;
  int m = blockIdx.x * 4 + wid;
  int t = m >> 8, q = m & (NQ - 1);
  int obase = m * KK;  // m == t*NQ + q

  float Qw = Tm[t * 7 + 0], Qx = Tm[t * 7 + 1], Qy = Tm[t * 7 + 2], Qz = Tm[t * 7 + 3];
  float c0 = qcoord[q * 3 + 0], c1 = qcoord[q * 3 + 1], c2 = qcoord[q * 3 + 2];
  double dr0, dr1, dr2;
  quat_rot_d((double)Qw, (double)Qx, (double)Qy, (double)Qz,
             (double)c0, (double)c1, (double)c2, dr0, dr1, dr2);
  float qr0 = (float)dr0, qr1 = (float)dr1, qr2 = (float)dr2;

  if (lane < KK) {
    s_kidx[wid][lane] = g_kidx[obase + lane];
    s_kd[wid][lane] = g_kd[obase + lane];
  }

  // rbf table: 16 k x 8 centers (wave-private LDS, no barrier)
  for (int kr = lane; kr < KK * NBB; kr += 64) {
    int k = kr >> 3, r = kr & 7;
    float d = s_kd[wid][k];
    float cc = (3.0f / 7.0f) * (float)r;
    float diff = d - cc;
    s_rbf[wid][kr] = expf(-4.0f * diff * diff);
  }

  // field[j] = gate[j] * sum_k (rbf[k,:] @ W_rbf[:,j]) * NF2[idx_k, j]
  for (int jj = 0; jj < 2; jj++) {
    int j = lane + 64 * jj;
    float wr[NBB];
#pragma unroll
    for (int r = 0; r < NBB; r++) wr[r] = W_rbf[r * DD + j];
    float acc = 0.0f;
#pragma unroll
    for (int k = 0; k < KK; k++) {
      float rw = 0.0f;
#pragma unroll
      for (int r = 0; r < NBB; r++) rw += s_rbf[wid][k * NBB + r] * wr[r];
      acc += rw * g_NF2[s_kidx[wid][k] * DD + j];
    }
    s_field[wid][j] = acc * g_gate[j];
  }

  // collapsed DTP: lane c<32 handles channel c; lin (r0..2), ang (r3..5)
  float r0 = 0, r1 = 0, r2 = 0, r3 = 0, r4 = 0, r5 = 0;
  if (lane < CHN) {
    int c = lane;
    float tF = s_field[wid][c];
    float u0 = s_field[wid][CHN + 3 * c + 0];
    float u1 = s_field[wid][CHN + 3 * c + 1];
    float u2 = s_field[wid][CHN + 3 * c + 2];
    float sc = qfeat[q * DD + c];
    float w0 = qfeat[q * DD + CHN + 3 * c + 0];
    float w1 = qfeat[q * DD + CHN + 3 * c + 1];
    float w2 = qfeat[q * DD + CHN + 3 * c + 2];
    float v0r, v1r, v2r;
    quat_rot(Qw, Qx, Qy, Qz, w0, w1, w2, v0r, v1r, v2r);
    float cx0 = v1r * u2 - v2r * u1;
    float cx1 = v2r * u0 - v0r * u2;
    float cx2 = v0r * u1 - v1r * u0;
    float Al = g_coef[c], Bl = g_coef[32 + c], Cl = g_coef[64 + c];
    float Aa = g_coef[96 + c], Ba = g_coef[128 + c], Ca = g_coef[160 + c];
    float su = Al * sc, bt = Bl * tF;
    r0 = su * u0 + bt * v0r + Cl * cx0;
    r1 = su * u1 + bt * v1r + Cl * cx1;
    r2 = su * u2 + bt * v2r + Cl * cx2;
    float sa = Aa * sc, ba = Ba * tF;
    r3 = sa * u0 + ba * v0r + Ca * cx0;
    r4 = sa * u1 + ba * v1r + Ca * cx1;
    r5 = sa * u2 + ba * v2r + Ca * cx2;
  }
#pragma unroll
  for (int off = 32; off > 0; off >>= 1) {
    r0 += __shfl_xor(r0, off, 64);
    r1 += __shfl_xor(r1, off, 64);
    r2 += __shfl_xor(r2, off, 64);
    r3 += __shfl_xor(r3, off, 64);
    r4 += __shfl_xor(r4, off, 64);
    r5 += __shfl_xor(r5, off, 64);
  }
  if (lane == 0) {
    float wq = qwgt[q];
    // orbital: cross(query_coord, R^-1 lin) = R^-1 cross(R*query_coord, lin)
    float o0 = qr1 * r2 - qr2 * r1;
    float o1 = qr2 * r0 - qr0 * r2;
    float o2 = qr0 * r1 - qr1 * r0;
    const float IA = 0.70710678118654752f;  // 1/ANG_MULT
    int pbase = m * 6;
    g_part[pbase + 0] = wq * r0;
    g_part[pbase + 1] = wq * r1;
    g_part[pbase + 2] = wq * r2;
    g_part[pbase + 3] = wq * (o0 + r3 * IA);
    g_part[pbase + 4] = wq * (o1 + r4 * IA);
    g_part[pbase + 5] = wq * (o2 + r5 * IA);
  }
}

// One block per t: sum 256 q-partials (shuffle + LDS), rotate by q^-1, write out.
__global__ __launch_bounds__(256) void reduce_kernel(const float* __restrict__ Tm,
                                                     float* __restrict__ out) {
  __shared__ float s_sum[4][6];
  int t = blockIdx.x;
  int lane = threadIdx.x & 63;
  int wid = threadIdx.x >> 6;
  int q = threadIdx.x;
  float v[6];
#pragma unroll
  for (int c = 0; c < 6; c++) v[c] = g_part[(t * NQ + q) * 6 + c];
#pragma unroll
  for (int off = 32; off > 0; off >>= 1) {
#pragma unroll
    for (int c = 0; c < 6; c++) v[c] += __shfl_xor(v[c], off, 64);
  }
  if (lane == 0) {
#pragma unroll
    for (int c = 0; c < 6; c++) s_sum[wid][c] = v[c];
  }
  __syncthreads();
  if (threadIdx.x == 0) {
    float sL0 = 0, sL1 = 0, sL2 = 0, sA0 = 0, sA1 = 0, sA2 = 0;
#pragma unroll
    for (int ww = 0; ww < 4; ww++) {
      sL0 += s_sum[ww][0]; sL1 += s_sum[ww][1]; sL2 += s_sum[ww][2];
      sA0 += s_sum[ww][3]; sA1 += s_sum[ww][4]; sA2 += s_sum[ww][5];
    }
    float Qw = Tm[t * 7 + 0], Qx = -Tm[t * 7 + 1], Qy = -Tm[t * 7 + 2], Qz = -Tm[t * 7 + 3];
    float a0, a1, a2, l0, l1, l2;
    quat_rot(Qw, Qx, Qy, Qz, sA0, sA1, sA2, a0, a1, a2);
    quat_rot(Qw, Qx, Qy, Qz, sL0, sL1, sL2, l0, l1, l2);
    out[t * 3 + 0] = a0;
    out[t * 3 + 1] = a1;
    out[t * 3 + 2] = a2;
    out[NT * 3 + t * 3 + 0] = l0;
    out[NT * 3 + t * 3 + 1] = l1;
    out[NT * 3 + t * 3 + 2] = l2;
  }
}

extern "C" void kernel_launch(void* const* d_in, const int* in_sizes, int n_in,
                              void* d_out, int out_size, void* d_ws, size_t ws_size,
                              hipStream_t stream) {
  const float* T      = (const float*)d_in[0];
  const float* qwgt   = (const float*)d_in[1];
  const float* qfeat  = (const float*)d_in[2];
  const float* qcoord = (const float*)d_in[3];
  const float* nfeat  = (const float*)d_in[4];
  const float* ncoord = (const float*)d_in[5];
  const float* temb   = (const float*)d_in[6];
  const float* W_ext  = (const float*)d_in[7];
  const float* W_rbf  = (const float*)d_in[8];
  const float* W_time = (const float*)d_in[9];
  const float* wp_lin = (const float*)d_in[10];
  // d_in[11] W_scal_lin: dead ([:,1:] drops the scalar channel)
  const float* Wv_lin = (const float*)d_in[12];
  const float* wp_ang = (const float*)d_in[13];
  // d_in[14] W_scal_ang: dead
  const float* Wv_ang = (const float*)d_in[15];
  const int* qbatch   = (const int*)d_in[16];
  const int* nbatch   = (const int*)d_in[17];
  float* out = (float*)d_out;

  prep_kernel<<<513, 256, 0, stream>>>(nfeat, W_ext, nbatch, temb, W_time,
                                       wp_lin, Wv_lin, wp_ang, Wv_ang);
  select_kernel<<<(NTG * NQ) / 4, 256, 0, stream>>>(T, qcoord, ncoord, qbatch);
  epi_kernel<<<(NT * NQ) / 4, 256, 0, stream>>>(T, qwgt, qfeat, qcoord, W_rbf);
  reduce_kernel<<<NT, 256, 0, stream>>>(T, out);
}